// Round 10
// baseline (259.334 us; speedup 1.0000x reference)
//
#include <hip/hip_runtime.h>
#include <stdint.h>
#include <stddef.h>

// Problem geometry
#define BROWS  16384
#define SROWS  8192
#define FDIM   512
#define NCHUNK 8                    // one S-chunk per XCD (L2-resident: 1 MB)
#define SCHUNK (SROWS / NCHUNK)     // 1024
#define BM     256                  // X rows per block
#define BN     256                  // S cols per S-tile
#define BK     64                   // K per staged chunk
#define NSTILE (SCHUNK / BN)        // 4
#define NKC    (FDIM / BK)          // 8
#define NC     (NSTILE * NKC)       // 32 chunks per block

#define LOG2E 1.44269504088896340736f

typedef __bf16 bf16x8 __attribute__((ext_vector_type(8)));
typedef float  f32x4  __attribute__((ext_vector_type(4)));

__device__ inline void gload16(const void* g, void* l) {
  __builtin_amdgcn_global_load_lds(
      (const __attribute__((address_space(1))) void*)g,
      (__attribute__((address_space(3))) void*)l, 16, 0, 0);
}

// ---------------------------------------------------------------------------
// Prep S: f32 -> bf16, lc2[s] = log2(coeff[s]) - g*log2e*||s||^2  (validated)
// ---------------------------------------------------------------------------
__global__ __launch_bounds__(256) void prep_s_kernel(
    const float* __restrict__ S, const float* __restrict__ coeff,
    const float* __restrict__ gamma, __bf16* __restrict__ Sb,
    float* __restrict__ lc2)
{
  const int lane = threadIdx.x & 63;
  const int wid  = threadIdx.x >> 6;
  const int row  = (blockIdx.x << 2) + wid;
  const float* src = S + ((size_t)row << 9) + (lane << 3);
  float4 a = ((const float4*)src)[0];
  float4 b = ((const float4*)src)[1];
  float sq = a.x*a.x + a.y*a.y + a.z*a.z + a.w*a.w +
             b.x*b.x + b.y*b.y + b.z*b.z + b.w*b.w;
  bf16x8 v;
  v[0]=(__bf16)a.x; v[1]=(__bf16)a.y; v[2]=(__bf16)a.z; v[3]=(__bf16)a.w;
  v[4]=(__bf16)b.x; v[5]=(__bf16)b.y; v[6]=(__bf16)b.z; v[7]=(__bf16)b.w;
  *(bf16x8*)(Sb + ((size_t)row << 9) + (lane << 3)) = v;
  #pragma unroll
  for (int m = 1; m < 64; m <<= 1) sq += __shfl_xor(sq, m, 64);
  if (lane == 0) lc2[row] = log2f(coeff[row]) - gamma[0] * LOG2E * sq;
}

// ---------------------------------------------------------------------------
// Prep X: f32 -> bf16, ex[row] = exp2(-g*log2e*||x||^2)
// ---------------------------------------------------------------------------
__global__ __launch_bounds__(256) void prep_x_kernel(
    const float* __restrict__ X, const float* __restrict__ gamma,
    __bf16* __restrict__ Xb, float* __restrict__ ex)
{
  const int lane = threadIdx.x & 63;
  const int wid  = threadIdx.x >> 6;
  const int row  = (blockIdx.x << 2) + wid;
  const float* src = X + ((size_t)row << 9) + (lane << 3);
  float4 a = ((const float4*)src)[0];
  float4 b = ((const float4*)src)[1];
  float sq = a.x*a.x + a.y*a.y + a.z*a.z + a.w*a.w +
             b.x*b.x + b.y*b.y + b.z*b.z + b.w*b.w;
  bf16x8 v;
  v[0]=(__bf16)a.x; v[1]=(__bf16)a.y; v[2]=(__bf16)a.z; v[3]=(__bf16)a.w;
  v[4]=(__bf16)b.x; v[5]=(__bf16)b.y; v[6]=(__bf16)b.z; v[7]=(__bf16)b.w;
  *(bf16x8*)(Xb + ((size_t)row << 9) + (lane << 3)) = v;
  #pragma unroll
  for (int m = 1; m < 64; m <<= 1) sq += __shfl_xor(sq, m, 64);
  if (lane == 0) ex[row] = exp2f(-gamma[0] * LOG2E * sq);
}

// ---------------------------------------------------------------------------
// Main: 2D register-blocked fused RBF-GEMM (R9 structure, register-budget fix).
// Block 512 thr = 8 waves (2M x 4N); wave computes 128x64 via 16x16x32 MFMA
// (M_rep=8, N_rep=4; acc = 128 VGPR). __launch_bounds__(512,1): 8-wave block
// => hardware cap 256 VGPR/wave (2 waves/SIMD) — fits ~230, no spill.
// chunk = blockIdx&7 => each XCD owns ONE 1 MB S-chunk (L2-resident; B
// re-staging = L2 hits). A+B tiles double-buffered in LDS (2 x 64 KB), XOR
// swizzle via pre-swizzled global source (dst linear) + swizzled ds_read.
// Per K-chunk: vmcnt(0) [issued a full chunk earlier] -> barrier -> STAGE
// next (post-barrier => dbuf race-free) -> 64 MFMA.
// ---------------------------------------------------------------------------
__global__ __launch_bounds__(512, 1) void ocsvm_main_kernel(
    const __bf16* __restrict__ Xb, const __bf16* __restrict__ Sb,
    const float* __restrict__ lc2, const float* __restrict__ ex,
    const float* __restrict__ gamma, float* __restrict__ partials)
{
  __shared__ char lds[131072];   // 2 x (A 32 KB + B 32 KB)
  const int tid  = threadIdx.x;
  const int lane = tid & 63;
  const int wid  = tid >> 6;
  const int wm   = wid >> 2;        // 0..1  (M group: 128 rows)
  const int wn   = wid & 3;         // 0..3  (N group: 64 cols)
  const int lr   = lane & 15;
  const int hi   = lane >> 4;

  // one S-chunk per XCD; all 64 m-tiles iterate within the XCD
  const int bx      = blockIdx.x;
  const int chunkid = bx & 7;
  const int mtile   = bx >> 3;
  const int m0      = mtile * BM;
  const int chunk0  = chunkid * SCHUNK;

  const float K2 = 2.0f * gamma[0] * LOG2E;

  const char* xb = (const char*)Xb;
  const char* sb = (const char*)Sb;
  const int r0     = tid >> 3;                            // staging row 0..63
  const int srcoff = ((tid & 7) << 4) ^ ((r0 & 7) << 4);  // pre-swizzled src byte

#define STAGE(bufsel, c)                                                      \
  { const int st_ = (c) >> 3, kc_ = (c) & 7;                                  \
    const char* asrc_ = xb + (((size_t)(m0 + r0)) << 10) + (kc_ << 7) + srcoff; \
    const char* bsrc_ = sb + (((size_t)(chunk0 + (st_ << 8) + r0)) << 10)     \
                           + (kc_ << 7) + srcoff;                             \
    char* ad_ = &lds[(bufsel) * 65536 + (tid << 4)];                          \
    _Pragma("unroll")                                                         \
    for (int j = 0; j < 4; ++j) {                                             \
      gload16(asrc_ + j * 65536, ad_ + j * 8192);                             \
      gload16(bsrc_ + j * 65536, ad_ + 32768 + j * 8192);                     \
    } }

  // frag-read swizzled k-offsets (bits 4-6): (ks*64 + hi*16) ^ ((lr&7)<<4)
  const int sw0 = (hi << 4) ^ ((lr & 7) << 4);
  const int sw1 = sw0 ^ 64;

  float score[8][4];
  #pragma unroll
  for (int mi = 0; mi < 8; ++mi)
    #pragma unroll
    for (int j = 0; j < 4; ++j) score[mi][j] = 0.0f;

  STAGE(0, 0);   // prologue

  int c = 0;
  for (int st = 0; st < NSTILE; ++st) {
    f32x4 acc[8][4];
    #pragma unroll
    for (int mi = 0; mi < 8; ++mi)
      #pragma unroll
      for (int ni = 0; ni < 4; ++ni) acc[mi][ni] = (f32x4){0.f, 0.f, 0.f, 0.f};

    for (int kc = 0; kc < NKC; ++kc, ++c) {
      // buf-c loads were issued one full chunk of compute ago
      asm volatile("s_waitcnt vmcnt(0)" ::: "memory");
      __builtin_amdgcn_s_barrier();
      asm volatile("" ::: "memory");
      if (c + 1 < NC) STAGE((c + 1) & 1, c + 1);   // post-barrier: dbuf-safe

      const char* bA = &lds[(c & 1) * 65536 + wm * 16384 + lr * 128];
      const char* bB = &lds[(c & 1) * 65536 + 32768 + (wn << 13) + lr * 128];

      #pragma unroll
      for (int ks = 0; ks < 2; ++ks) {
        const int swk = ks ? sw1 : sw0;
        bf16x8 bfr[4], af[8];
        #pragma unroll
        for (int ni = 0; ni < 4; ++ni)
          bfr[ni] = *(const bf16x8*)(bB + swk + ni * 2048);
        #pragma unroll
        for (int mi = 0; mi < 8; ++mi)
          af[mi] = *(const bf16x8*)(bA + swk + mi * 2048);
        #pragma unroll
        for (int mi = 0; mi < 8; ++mi)
          #pragma unroll
          for (int ni = 0; ni < 4; ++ni)
            acc[mi][ni] = __builtin_amdgcn_mfma_f32_16x16x32_bf16(
                af[mi], bfr[ni], acc[mi][ni], 0, 0, 0);
      }
    }

    // epilogue for S-tile st: cols = chunk0 + st*256 + wn*64 + ni*16 + lr
    const float* lc = lc2 + chunk0 + (st << 8) + (wn << 6) + lr;
    const float l0 = lc[0], l1 = lc[16], l2 = lc[32], l3 = lc[48];
    #pragma unroll
    for (int mi = 0; mi < 8; ++mi)
      #pragma unroll
      for (int j = 0; j < 4; ++j)
        score[mi][j] += __builtin_amdgcn_exp2f(__builtin_fmaf(K2, acc[mi][0][j], l0))
                      + __builtin_amdgcn_exp2f(__builtin_fmaf(K2, acc[mi][1][j], l1))
                      + __builtin_amdgcn_exp2f(__builtin_fmaf(K2, acc[mi][2][j], l2))
                      + __builtin_amdgcn_exp2f(__builtin_fmaf(K2, acc[mi][3][j], l3));
  }

  // fold 16 col-lanes, scale by e_x, write per-(chunk,wn) partial
  // C layout (m89): col = lane&15, row = (lane>>4)*4 + reg
  #pragma unroll
  for (int mi = 0; mi < 8; ++mi)
    #pragma unroll
    for (int j = 0; j < 4; ++j) {
      float v = score[mi][j];
      v += __shfl_xor(v, 1, 64);
      v += __shfl_xor(v, 2, 64);
      v += __shfl_xor(v, 4, 64);
      v += __shfl_xor(v, 8, 64);
      const int row = m0 + (wm << 7) + (mi << 4) + (hi << 2) + j;
      if (lr == 0)
        partials[(size_t)((chunkid << 2) + wn) * BROWS + row] = ex[row] * v;
    }
#undef STAGE
}

// ---------------------------------------------------------------------------
// Final: sum 32 partial slices (8 chunks x 4 wn), subtract rho.
// ---------------------------------------------------------------------------
__global__ __launch_bounds__(256) void reduce_kernel(
    const float* __restrict__ partials, const float* __restrict__ rho,
    float* __restrict__ out)
{
  const int i = blockIdx.x * 256 + threadIdx.x;
  float s = 0.0f;
  #pragma unroll
  for (int k = 0; k < 32; ++k) s += partials[(size_t)k * BROWS + i];
  out[i] = s - rho[0];
}

extern "C" void kernel_launch(void* const* d_in, const int* in_sizes, int n_in,
                              void* d_out, int out_size, void* d_ws, size_t ws_size,
                              hipStream_t stream) {
  const float* X     = (const float*)d_in[0];   // [16384,512] f32
  const float* S     = (const float*)d_in[1];   // [8192,512]  f32
  const float* coeff = (const float*)d_in[2];   // [1,8192]    f32
  const float* rho   = (const float*)d_in[3];   // [1]         f32
  const float* gamma = (const float*)d_in[4];   // scalar      f32
  float* out = (float*)d_out;

  // ws: Sb 8MB | Xb 16MB | lc2 32KB | ex 64KB | partials 2MB  (~26.1 MB)
  char* ws = (char*)d_ws;
  __bf16* Sb    = (__bf16*)ws;
  __bf16* Xbuf  = (__bf16*)(ws + ((size_t)SROWS * FDIM * 2));
  float*  lc2   = (float*)(ws + ((size_t)SROWS * FDIM * 2) + ((size_t)BROWS * FDIM * 2));
  float*  ex    = lc2 + SROWS;
  float*  parts = ex + BROWS;

  prep_s_kernel<<<SROWS / 4, 256, 0, stream>>>(S, coeff, gamma, Sb, lc2);
  prep_x_kernel<<<BROWS / 4, 256, 0, stream>>>(X, gamma, Xbuf, ex);
  ocsvm_main_kernel<<<NCHUNK * 64, 512, 0, stream>>>(Xbuf, Sb, lc2, ex, gamma, parts);
  reduce_kernel<<<BROWS / 256, 256, 0, stream>>>(parts, rho, out);
}

// Round 11
// 219.398 us; speedup vs baseline: 1.1820x; 1.1820x over previous
//
#include <hip/hip_runtime.h>
#include <stdint.h>
#include <stddef.h>

// Problem geometry
#define BROWS  16384
#define SROWS  8192
#define FDIM   512
#define NCHUNK 8                    // one S-chunk per XCD (L2-resident: 1 MB)
#define SCHUNK (SROWS / NCHUNK)     // 1024
#define BM     256                  // X rows per block
#define BN     256                  // S cols per S-tile
#define BK     64                   // K per staged chunk
#define NSTILE (SCHUNK / BN)        // 4
#define NKC    (FDIM / BK)          // 8
#define NC     (NSTILE * NKC)       // 32 chunks per block

#define LOG2E 1.44269504088896340736f

typedef __bf16 bf16x8 __attribute__((ext_vector_type(8)));
typedef float  f32x4  __attribute__((ext_vector_type(4)));

__device__ inline void gload16(const void* g, void* l) {
  __builtin_amdgcn_global_load_lds(
      (const __attribute__((address_space(1))) void*)g,
      (__attribute__((address_space(3))) void*)l, 16, 0, 0);
}

// ---------------------------------------------------------------------------
// Prep S: f32 -> bf16, lc2[s] = log2(coeff[s]) - g*log2e*||s||^2  (validated)
// ---------------------------------------------------------------------------
__global__ __launch_bounds__(256) void prep_s_kernel(
    const float* __restrict__ S, const float* __restrict__ coeff,
    const float* __restrict__ gamma, __bf16* __restrict__ Sb,
    float* __restrict__ lc2)
{
  const int lane = threadIdx.x & 63;
  const int wid  = threadIdx.x >> 6;
  const int row  = (blockIdx.x << 2) + wid;
  const float* src = S + ((size_t)row << 9) + (lane << 3);
  float4 a = ((const float4*)src)[0];
  float4 b = ((const float4*)src)[1];
  float sq = a.x*a.x + a.y*a.y + a.z*a.z + a.w*a.w +
             b.x*b.x + b.y*b.y + b.z*b.z + b.w*b.w;
  bf16x8 v;
  v[0]=(__bf16)a.x; v[1]=(__bf16)a.y; v[2]=(__bf16)a.z; v[3]=(__bf16)a.w;
  v[4]=(__bf16)b.x; v[5]=(__bf16)b.y; v[6]=(__bf16)b.z; v[7]=(__bf16)b.w;
  *(bf16x8*)(Sb + ((size_t)row << 9) + (lane << 3)) = v;
  #pragma unroll
  for (int m = 1; m < 64; m <<= 1) sq += __shfl_xor(sq, m, 64);
  if (lane == 0) lc2[row] = log2f(coeff[row]) - gamma[0] * LOG2E * sq;
}

// ---------------------------------------------------------------------------
// Prep X: f32 -> bf16, ex[row] = exp2(-g*log2e*||x||^2)
// ---------------------------------------------------------------------------
__global__ __launch_bounds__(256) void prep_x_kernel(
    const float* __restrict__ X, const float* __restrict__ gamma,
    __bf16* __restrict__ Xb, float* __restrict__ ex)
{
  const int lane = threadIdx.x & 63;
  const int wid  = threadIdx.x >> 6;
  const int row  = (blockIdx.x << 2) + wid;
  const float* src = X + ((size_t)row << 9) + (lane << 3);
  float4 a = ((const float4*)src)[0];
  float4 b = ((const float4*)src)[1];
  float sq = a.x*a.x + a.y*a.y + a.z*a.z + a.w*a.w +
             b.x*b.x + b.y*b.y + b.z*b.z + b.w*b.w;
  bf16x8 v;
  v[0]=(__bf16)a.x; v[1]=(__bf16)a.y; v[2]=(__bf16)a.z; v[3]=(__bf16)a.w;
  v[4]=(__bf16)b.x; v[5]=(__bf16)b.y; v[6]=(__bf16)b.z; v[7]=(__bf16)b.w;
  *(bf16x8*)(Xb + ((size_t)row << 9) + (lane << 3)) = v;
  #pragma unroll
  for (int m = 1; m < 64; m <<= 1) sq += __shfl_xor(sq, m, 64);
  if (lane == 0) ex[row] = exp2f(-gamma[0] * LOG2E * sq);
}

// ---------------------------------------------------------------------------
// Main: 2D register-blocked fused RBF-GEMM — spill-fixed variant.
// Block 512 thr = 8 waves (2M x 4N); wave = 128x64 output (M_rep=8, N_rep=4,
// acc 128 regs in AGPR half of the unified file). Live-range diet vs R9/R10:
// per k-slice load 4 B-frags (16 VGPR), then A in two halves of 4 (16 VGPR),
// so peak VGPR demand ~225 < the 256/wave cap at 2 waves/SIMD -> no scratch.
// chunk = blockIdx&7: one 1 MB S-chunk per XCD (L2-resident B re-stage).
// A+B double-buffered in LDS (2 x 64 KB), XOR swizzle via pre-swizzled
// global source (linear gload_lds dst) + swizzled ds_read (rule #21).
// Per K-chunk: vmcnt(0) [loads issued a full chunk earlier -> cheap] ->
// barrier -> STAGE next (post-barrier => dbuf race-free) -> 64 MFMA with
// setprio(1) (T5). Per S-tile epilogue: score += exp2(K2*cross + lc2).
// ---------------------------------------------------------------------------
__global__ __launch_bounds__(512, 2) void ocsvm_main_kernel(
    const __bf16* __restrict__ Xb, const __bf16* __restrict__ Sb,
    const float* __restrict__ lc2, const float* __restrict__ ex,
    const float* __restrict__ gamma, float* __restrict__ partials)
{
  __shared__ char lds[131072];   // 2 x (A 32 KB + B 32 KB)
  const int tid  = threadIdx.x;
  const int lane = tid & 63;
  const int wid  = tid >> 6;
  const int wm   = wid >> 2;        // 0..1  (M group: 128 rows)
  const int wn   = wid & 3;         // 0..3  (N group: 64 cols)
  const int lr   = lane & 15;
  const int hi   = lane >> 4;

  const int bx      = blockIdx.x;
  const int chunkid = bx & 7;
  const int mtile   = bx >> 3;
  const int m0      = mtile * BM;
  const int chunk0  = chunkid * SCHUNK;

  const float K2 = 2.0f * gamma[0] * LOG2E;

  const char* xb = (const char*)Xb;
  const char* sb = (const char*)Sb;
  const int r0     = tid >> 3;                            // staging row 0..63
  const int srcoff = ((tid & 7) << 4) ^ ((r0 & 7) << 4);  // pre-swizzled src byte

#define STAGE(bufsel, c)                                                      \
  { const int st_ = (c) >> 3, kc_ = (c) & 7;                                  \
    const char* asrc_ = xb + (((size_t)(m0 + r0)) << 10) + (kc_ << 7) + srcoff; \
    const char* bsrc_ = sb + (((size_t)(chunk0 + (st_ << 8) + r0)) << 10)     \
                           + (kc_ << 7) + srcoff;                             \
    char* ad_ = &lds[(bufsel) * 65536 + (tid << 4)];                          \
    _Pragma("unroll")                                                         \
    for (int j = 0; j < 4; ++j) {                                             \
      gload16(asrc_ + j * 65536, ad_ + j * 8192);                             \
      gload16(bsrc_ + j * 65536, ad_ + 32768 + j * 8192);                     \
    } }

  // frag-read swizzled k-offsets (bits 4-6): (ks*64 + hi*16) ^ ((lr&7)<<4)
  const int sw0 = (hi << 4) ^ ((lr & 7) << 4);
  const int sw1 = sw0 ^ 64;

  float score[8][4];
  #pragma unroll
  for (int mi = 0; mi < 8; ++mi)
    #pragma unroll
    for (int j = 0; j < 4; ++j) score[mi][j] = 0.0f;

  STAGE(0, 0);   // prologue

  int c = 0;
  for (int st = 0; st < NSTILE; ++st) {
    f32x4 acc[8][4];
    #pragma unroll
    for (int mi = 0; mi < 8; ++mi)
      #pragma unroll
      for (int ni = 0; ni < 4; ++ni) acc[mi][ni] = (f32x4){0.f, 0.f, 0.f, 0.f};

    for (int kc = 0; kc < NKC; ++kc, ++c) {
      // buf-c loads were issued one full chunk of compute ago
      asm volatile("s_waitcnt vmcnt(0)" ::: "memory");
      __builtin_amdgcn_s_barrier();
      asm volatile("" ::: "memory");
      if (c + 1 < NC) STAGE((c + 1) & 1, c + 1);   // post-barrier: dbuf-safe

      const char* bA = &lds[(c & 1) * 65536 + wm * 16384 + lr * 128];
      const char* bB = &lds[(c & 1) * 65536 + 32768 + (wn << 13) + lr * 128];

      __builtin_amdgcn_s_setprio(1);
      #pragma unroll
      for (int ks = 0; ks < 2; ++ks) {
        const int swk = ks ? sw1 : sw0;
        bf16x8 b0 = *(const bf16x8*)(bB + swk);
        bf16x8 b1 = *(const bf16x8*)(bB + swk + 2048);
        bf16x8 b2 = *(const bf16x8*)(bB + swk + 4096);
        bf16x8 b3 = *(const bf16x8*)(bB + swk + 6144);
        #pragma unroll
        for (int mh = 0; mh < 2; ++mh) {
          const char* pa = bA + swk + mh * 8192;
          bf16x8 a0 = *(const bf16x8*)(pa);
          bf16x8 a1 = *(const bf16x8*)(pa + 2048);
          bf16x8 a2 = *(const bf16x8*)(pa + 4096);
          bf16x8 a3 = *(const bf16x8*)(pa + 6144);
          const int mb = mh << 2;
          acc[mb+0][0] = __builtin_amdgcn_mfma_f32_16x16x32_bf16(a0, b0, acc[mb+0][0], 0, 0, 0);
          acc[mb+0][1] = __builtin_amdgcn_mfma_f32_16x16x32_bf16(a0, b1, acc[mb+0][1], 0, 0, 0);
          acc[mb+0][2] = __builtin_amdgcn_mfma_f32_16x16x32_bf16(a0, b2, acc[mb+0][2], 0, 0, 0);
          acc[mb+0][3] = __builtin_amdgcn_mfma_f32_16x16x32_bf16(a0, b3, acc[mb+0][3], 0, 0, 0);
          acc[mb+1][0] = __builtin_amdgcn_mfma_f32_16x16x32_bf16(a1, b0, acc[mb+1][0], 0, 0, 0);
          acc[mb+1][1] = __builtin_amdgcn_mfma_f32_16x16x32_bf16(a1, b1, acc[mb+1][1], 0, 0, 0);
          acc[mb+1][2] = __builtin_amdgcn_mfma_f32_16x16x32_bf16(a1, b2, acc[mb+1][2], 0, 0, 0);
          acc[mb+1][3] = __builtin_amdgcn_mfma_f32_16x16x32_bf16(a1, b3, acc[mb+1][3], 0, 0, 0);
          acc[mb+2][0] = __builtin_amdgcn_mfma_f32_16x16x32_bf16(a2, b0, acc[mb+2][0], 0, 0, 0);
          acc[mb+2][1] = __builtin_amdgcn_mfma_f32_16x16x32_bf16(a2, b1, acc[mb+2][1], 0, 0, 0);
          acc[mb+2][2] = __builtin_amdgcn_mfma_f32_16x16x32_bf16(a2, b2, acc[mb+2][2], 0, 0, 0);
          acc[mb+2][3] = __builtin_amdgcn_mfma_f32_16x16x32_bf16(a2, b3, acc[mb+2][3], 0, 0, 0);
          acc[mb+3][0] = __builtin_amdgcn_mfma_f32_16x16x32_bf16(a3, b0, acc[mb+3][0], 0, 0, 0);
          acc[mb+3][1] = __builtin_amdgcn_mfma_f32_16x16x32_bf16(a3, b1, acc[mb+3][1], 0, 0, 0);
          acc[mb+3][2] = __builtin_amdgcn_mfma_f32_16x16x32_bf16(a3, b2, acc[mb+3][2], 0, 0, 0);
          acc[mb+3][3] = __builtin_amdgcn_mfma_f32_16x16x32_bf16(a3, b3, acc[mb+3][3], 0, 0, 0);
        }
      }
      __builtin_amdgcn_s_setprio(0);
    }

    // epilogue for S-tile st: cols = chunk0 + st*256 + wn*64 + ni*16 + lr
    const float* lc = lc2 + chunk0 + (st << 8) + (wn << 6) + lr;
    const float l0 = lc[0], l1 = lc[16], l2 = lc[32], l3 = lc[48];
    #pragma unroll
    for (int mi = 0; mi < 8; ++mi)
      #pragma unroll
      for (int j = 0; j < 4; ++j)
        score[mi][j] += __builtin_amdgcn_exp2f(__builtin_fmaf(K2, acc[mi][0][j], l0))
                      + __builtin_amdgcn_exp2f(__builtin_fmaf(K2, acc[mi][1][j], l1))
                      + __builtin_amdgcn_exp2f(__builtin_fmaf(K2, acc[mi][2][j], l2))
                      + __builtin_amdgcn_exp2f(__builtin_fmaf(K2, acc[mi][3][j], l3));
  }

  // fold 16 col-lanes, scale by e_x, write per-(chunk,wn) partial
  // C layout (m89): col = lane&15, row = (lane>>4)*4 + reg
  #pragma unroll
  for (int mi = 0; mi < 8; ++mi)
    #pragma unroll
    for (int j = 0; j < 4; ++j) {
      float v = score[mi][j];
      v += __shfl_xor(v, 1, 64);
      v += __shfl_xor(v, 2, 64);
      v += __shfl_xor(v, 4, 64);
      v += __shfl_xor(v, 8, 64);
      const int row = m0 + (wm << 7) + (mi << 4) + (hi << 2) + j;
      if (lr == 0)
        partials[(size_t)((chunkid << 2) + wn) * BROWS + row] = ex[row] * v;
    }
#undef STAGE
}

// ---------------------------------------------------------------------------
// Final: sum 32 partial slices (8 chunks x 4 wn), subtract rho.
// ---------------------------------------------------------------------------
__global__ __launch_bounds__(256) void reduce_kernel(
    const float* __restrict__ partials, const float* __restrict__ rho,
    float* __restrict__ out)
{
  const int i = blockIdx.x * 256 + threadIdx.x;
  float s = 0.0f;
  #pragma unroll
  for (int k = 0; k < 32; ++k) s += partials[(size_t)k * BROWS + i];
  out[i] = s - rho[0];
}

extern "C" void kernel_launch(void* const* d_in, const int* in_sizes, int n_in,
                              void* d_out, int out_size, void* d_ws, size_t ws_size,
                              hipStream_t stream) {
  const float* X     = (const float*)d_in[0];   // [16384,512] f32
  const float* S     = (const float*)d_in[1];   // [8192,512]  f32
  const float* coeff = (const float*)d_in[2];   // [1,8192]    f32
  const float* rho   = (const float*)d_in[3];   // [1]         f32
  const float* gamma = (const float*)d_in[4];   // scalar      f32
  float* out = (float*)d_out;

  // ws: Sb 8MB | Xb 16MB | lc2 32KB | ex 64KB | partials 2MB  (~26.1 MB)
  char* ws = (char*)d_ws;
  __bf16* Sb    = (__bf16*)ws;
  __bf16* Xbuf  = (__bf16*)(ws + ((size_t)SROWS * FDIM * 2));
  float*  lc2   = (float*)(ws + ((size_t)SROWS * FDIM * 2) + ((size_t)BROWS * FDIM * 2));
  float*  ex    = lc2 + SROWS;
  float*  parts = ex + BROWS;

  prep_s_kernel<<<SROWS / 4, 256, 0, stream>>>(S, coeff, gamma, Sb, lc2);
  prep_x_kernel<<<BROWS / 4, 256, 0, stream>>>(X, gamma, Xbuf, ex);
  ocsvm_main_kernel<<<NCHUNK * 64, 512, 0, stream>>>(Xbuf, Sb, lc2, ex, gamma, parts);
  reduce_kernel<<<BROWS / 256, 256, 0, stream>>>(parts, rho, out);
}

// Round 12
// 216.854 us; speedup vs baseline: 1.1959x; 1.0117x over previous
//
#include <hip/hip_runtime.h>
#include <stdint.h>
#include <stddef.h>

// Problem geometry
#define BROWS  16384
#define SROWS  8192
#define FDIM   512
#define NCHUNK 8                    // one S-chunk per XCD (L2-resident: 1 MB)
#define SCHUNK (SROWS / NCHUNK)     // 1024
#define BM     256                  // X rows per block
#define BN     256                  // S cols per S-tile
#define BK     64                   // K per staged chunk
#define NSTILE (SCHUNK / BN)        // 4
#define NKC    (FDIM / BK)          // 8
#define NC     (NSTILE * NKC)       // 32 chunks per block

#define LOG2E 1.44269504088896340736f

typedef __bf16 bf16x8 __attribute__((ext_vector_type(8)));
typedef float  f32x4  __attribute__((ext_vector_type(4)));

__device__ inline void gload16(const void* g, void* l) {
  __builtin_amdgcn_global_load_lds(
      (const __attribute__((address_space(1))) void*)g,
      (__attribute__((address_space(3))) void*)l, 16, 0, 0);
}

// ---------------------------------------------------------------------------
// Prep S: f32 -> bf16, lc2[s] = log2(coeff[s]) - g*log2e*||s||^2  (validated)
// ---------------------------------------------------------------------------
__global__ __launch_bounds__(256) void prep_s_kernel(
    const float* __restrict__ S, const float* __restrict__ coeff,
    const float* __restrict__ gamma, __bf16* __restrict__ Sb,
    float* __restrict__ lc2)
{
  const int lane = threadIdx.x & 63;
  const int wid  = threadIdx.x >> 6;
  const int row  = (blockIdx.x << 2) + wid;
  const float* src = S + ((size_t)row << 9) + (lane << 3);
  float4 a = ((const float4*)src)[0];
  float4 b = ((const float4*)src)[1];
  float sq = a.x*a.x + a.y*a.y + a.z*a.z + a.w*a.w +
             b.x*b.x + b.y*b.y + b.z*b.z + b.w*b.w;
  bf16x8 v;
  v[0]=(__bf16)a.x; v[1]=(__bf16)a.y; v[2]=(__bf16)a.z; v[3]=(__bf16)a.w;
  v[4]=(__bf16)b.x; v[5]=(__bf16)b.y; v[6]=(__bf16)b.z; v[7]=(__bf16)b.w;
  *(bf16x8*)(Sb + ((size_t)row << 9) + (lane << 3)) = v;
  #pragma unroll
  for (int m = 1; m < 64; m <<= 1) sq += __shfl_xor(sq, m, 64);
  if (lane == 0) lc2[row] = log2f(coeff[row]) - gamma[0] * LOG2E * sq;
}

// ---------------------------------------------------------------------------
// Prep X: f32 -> bf16, ex[row] = exp2(-g*log2e*||x||^2)
// ---------------------------------------------------------------------------
__global__ __launch_bounds__(256) void prep_x_kernel(
    const float* __restrict__ X, const float* __restrict__ gamma,
    __bf16* __restrict__ Xb, float* __restrict__ ex)
{
  const int lane = threadIdx.x & 63;
  const int wid  = threadIdx.x >> 6;
  const int row  = (blockIdx.x << 2) + wid;
  const float* src = X + ((size_t)row << 9) + (lane << 3);
  float4 a = ((const float4*)src)[0];
  float4 b = ((const float4*)src)[1];
  float sq = a.x*a.x + a.y*a.y + a.z*a.z + a.w*a.w +
             b.x*b.x + b.y*b.y + b.z*b.z + b.w*b.w;
  bf16x8 v;
  v[0]=(__bf16)a.x; v[1]=(__bf16)a.y; v[2]=(__bf16)a.z; v[3]=(__bf16)a.w;
  v[4]=(__bf16)b.x; v[5]=(__bf16)b.y; v[6]=(__bf16)b.z; v[7]=(__bf16)b.w;
  *(bf16x8*)(Xb + ((size_t)row << 9) + (lane << 3)) = v;
  #pragma unroll
  for (int m = 1; m < 64; m <<= 1) sq += __shfl_xor(sq, m, 64);
  if (lane == 0) ex[row] = exp2f(-gamma[0] * LOG2E * sq);
}

// ---------------------------------------------------------------------------
// Main: 2D register-blocked fused RBF-GEMM — LDS-score variant (spill kill).
// Block 512 thr = 8 waves (2M x 4N); wave = 128x64 (M_rep=8, N_rep=4,
// acc = 128 AGPR). The per-row score accumulator now lives in LDS
// (score_lds[256] + ds_add_f32 per S-tile after a 16-lane shfl reduce), so
// the VGPR half holds only frags (<=32 live, mh-split) + addressing ->
// ~100 < 128 cap -> no scratch.
// chunk = blockIdx&7: one 1 MB S-chunk per XCD (L2-resident B re-stage).
// A+B double-buffered in LDS (2 x 64 KB), XOR swizzle via pre-swizzled
// global source (linear gload_lds dst) + swizzled ds_read (rule #21).
// Per K-chunk: vmcnt(0) [loads issued a full chunk earlier -> cheap] ->
// barrier -> STAGE next (post-barrier => dbuf race-free) -> 64 MFMA (T5).
// ---------------------------------------------------------------------------
__global__ __launch_bounds__(512, 2) void ocsvm_main_kernel(
    const __bf16* __restrict__ Xb, const __bf16* __restrict__ Sb,
    const float* __restrict__ lc2, const float* __restrict__ ex,
    const float* __restrict__ gamma, float* __restrict__ partials)
{
  __shared__ char lds[131072];        // 2 x (A 32 KB + B 32 KB)
  __shared__ float score_lds[BM];     // per-row score accumulator
  const int tid  = threadIdx.x;
  const int lane = tid & 63;
  const int wid  = tid >> 6;
  const int wm   = wid >> 2;        // 0..1  (M group: 128 rows)
  const int wn   = wid & 3;         // 0..3  (N group: 64 cols)
  const int lr   = lane & 15;
  const int hi   = lane >> 4;

  const int bx      = blockIdx.x;
  const int chunkid = bx & 7;
  const int mtile   = bx >> 3;
  const int m0      = mtile * BM;
  const int chunk0  = chunkid * SCHUNK;

  const float K2 = 2.0f * gamma[0] * LOG2E;

  const char* xb = (const char*)Xb;
  const char* sb = (const char*)Sb;
  const int r0     = tid >> 3;                            // staging row 0..63
  const int srcoff = ((tid & 7) << 4) ^ ((r0 & 7) << 4);  // pre-swizzled src byte

#define STAGE(bufsel, c)                                                      \
  { const int st_ = (c) >> 3, kc_ = (c) & 7;                                  \
    const char* asrc_ = xb + (((size_t)(m0 + r0)) << 10) + (kc_ << 7) + srcoff; \
    const char* bsrc_ = sb + (((size_t)(chunk0 + (st_ << 8) + r0)) << 10)     \
                           + (kc_ << 7) + srcoff;                             \
    char* ad_ = &lds[(bufsel) * 65536 + (tid << 4)];                          \
    _Pragma("unroll")                                                         \
    for (int j = 0; j < 4; ++j) {                                             \
      gload16(asrc_ + j * 65536, ad_ + j * 8192);                             \
      gload16(bsrc_ + j * 65536, ad_ + 32768 + j * 8192);                     \
    } }

  // frag-read swizzled k-offsets (bits 4-6): (ks*64 + hi*16) ^ ((lr&7)<<4)
  const int sw0 = (hi << 4) ^ ((lr & 7) << 4);
  const int sw1 = sw0 ^ 64;

  STAGE(0, 0);   // prologue
  if (tid < BM) score_lds[tid] = 0.0f;   // init before first barrier

  int c = 0;
  for (int st = 0; st < NSTILE; ++st) {
    f32x4 acc[8][4];
    #pragma unroll
    for (int mi = 0; mi < 8; ++mi)
      #pragma unroll
      for (int ni = 0; ni < 4; ++ni) acc[mi][ni] = (f32x4){0.f, 0.f, 0.f, 0.f};

    for (int kc = 0; kc < NKC; ++kc, ++c) {
      // buf-c loads were issued one full chunk of compute ago
      asm volatile("s_waitcnt vmcnt(0)" ::: "memory");
      __builtin_amdgcn_s_barrier();
      asm volatile("" ::: "memory");
      if (c + 1 < NC) STAGE((c + 1) & 1, c + 1);   // post-barrier: dbuf-safe

      const char* bA = &lds[(c & 1) * 65536 + wm * 16384 + lr * 128];
      const char* bB = &lds[(c & 1) * 65536 + 32768 + (wn << 13) + lr * 128];

      __builtin_amdgcn_s_setprio(1);
      #pragma unroll
      for (int ks = 0; ks < 2; ++ks) {
        const int swk = ks ? sw1 : sw0;
        bf16x8 b0 = *(const bf16x8*)(bB + swk);
        bf16x8 b1 = *(const bf16x8*)(bB + swk + 2048);
        bf16x8 b2 = *(const bf16x8*)(bB + swk + 4096);
        bf16x8 b3 = *(const bf16x8*)(bB + swk + 6144);
        #pragma unroll
        for (int mh = 0; mh < 2; ++mh) {
          const char* pa = bA + swk + mh * 8192;
          bf16x8 a0 = *(const bf16x8*)(pa);
          bf16x8 a1 = *(const bf16x8*)(pa + 2048);
          bf16x8 a2 = *(const bf16x8*)(pa + 4096);
          bf16x8 a3 = *(const bf16x8*)(pa + 6144);
          const int mb = mh << 2;
          acc[mb+0][0] = __builtin_amdgcn_mfma_f32_16x16x32_bf16(a0, b0, acc[mb+0][0], 0, 0, 0);
          acc[mb+0][1] = __builtin_amdgcn_mfma_f32_16x16x32_bf16(a0, b1, acc[mb+0][1], 0, 0, 0);
          acc[mb+0][2] = __builtin_amdgcn_mfma_f32_16x16x32_bf16(a0, b2, acc[mb+0][2], 0, 0, 0);
          acc[mb+0][3] = __builtin_amdgcn_mfma_f32_16x16x32_bf16(a0, b3, acc[mb+0][3], 0, 0, 0);
          acc[mb+1][0] = __builtin_amdgcn_mfma_f32_16x16x32_bf16(a1, b0, acc[mb+1][0], 0, 0, 0);
          acc[mb+1][1] = __builtin_amdgcn_mfma_f32_16x16x32_bf16(a1, b1, acc[mb+1][1], 0, 0, 0);
          acc[mb+1][2] = __builtin_amdgcn_mfma_f32_16x16x32_bf16(a1, b2, acc[mb+1][2], 0, 0, 0);
          acc[mb+1][3] = __builtin_amdgcn_mfma_f32_16x16x32_bf16(a1, b3, acc[mb+1][3], 0, 0, 0);
          acc[mb+2][0] = __builtin_amdgcn_mfma_f32_16x16x32_bf16(a2, b0, acc[mb+2][0], 0, 0, 0);
          acc[mb+2][1] = __builtin_amdgcn_mfma_f32_16x16x32_bf16(a2, b1, acc[mb+2][1], 0, 0, 0);
          acc[mb+2][2] = __builtin_amdgcn_mfma_f32_16x16x32_bf16(a2, b2, acc[mb+2][2], 0, 0, 0);
          acc[mb+2][3] = __builtin_amdgcn_mfma_f32_16x16x32_bf16(a2, b3, acc[mb+2][3], 0, 0, 0);
          acc[mb+3][0] = __builtin_amdgcn_mfma_f32_16x16x32_bf16(a3, b0, acc[mb+3][0], 0, 0, 0);
          acc[mb+3][1] = __builtin_amdgcn_mfma_f32_16x16x32_bf16(a3, b1, acc[mb+3][1], 0, 0, 0);
          acc[mb+3][2] = __builtin_amdgcn_mfma_f32_16x16x32_bf16(a3, b2, acc[mb+3][2], 0, 0, 0);
          acc[mb+3][3] = __builtin_amdgcn_mfma_f32_16x16x32_bf16(a3, b3, acc[mb+3][3], 0, 0, 0);
        }
      }
      __builtin_amdgcn_s_setprio(0);
    }

    // epilogue for S-tile st: cols = chunk0 + st*256 + wn*64 + ni*16 + lr.
    // Transient per-lane exp-sum -> 16-lane shfl reduce -> ds_add_f32.
    const float* lc = lc2 + chunk0 + (st << 8) + (wn << 6) + lr;
    const float l0 = lc[0], l1 = lc[16], l2 = lc[32], l3 = lc[48];
    #pragma unroll
    for (int mi = 0; mi < 8; ++mi)
      #pragma unroll
      for (int j = 0; j < 4; ++j) {
        float v = __builtin_amdgcn_exp2f(__builtin_fmaf(K2, acc[mi][0][j], l0))
                + __builtin_amdgcn_exp2f(__builtin_fmaf(K2, acc[mi][1][j], l1))
                + __builtin_amdgcn_exp2f(__builtin_fmaf(K2, acc[mi][2][j], l2))
                + __builtin_amdgcn_exp2f(__builtin_fmaf(K2, acc[mi][3][j], l3));
        v += __shfl_xor(v, 1, 64);
        v += __shfl_xor(v, 2, 64);
        v += __shfl_xor(v, 4, 64);
        v += __shfl_xor(v, 8, 64);
        if (lr == 0)   // C layout (m89): row = (lane>>4)*4 + reg
          atomicAdd(&score_lds[(wm << 7) + (mi << 4) + (hi << 2) + j], v);
      }
  }

  __syncthreads();   // all ds_add_f32 retired
  if (tid < BM) {
    const int row = m0 + tid;
    partials[(size_t)chunkid * BROWS + row] = score_lds[tid] * ex[row];
  }
#undef STAGE
}

// ---------------------------------------------------------------------------
// Final: sum 8 chunk partials, subtract rho.
// ---------------------------------------------------------------------------
__global__ __launch_bounds__(256) void reduce_kernel(
    const float* __restrict__ partials, const float* __restrict__ rho,
    float* __restrict__ out)
{
  const int i = blockIdx.x * 256 + threadIdx.x;
  float s = 0.0f;
  #pragma unroll
  for (int k = 0; k < NCHUNK; ++k) s += partials[(size_t)k * BROWS + i];
  out[i] = s - rho[0];
}

extern "C" void kernel_launch(void* const* d_in, const int* in_sizes, int n_in,
                              void* d_out, int out_size, void* d_ws, size_t ws_size,
                              hipStream_t stream) {
  const float* X     = (const float*)d_in[0];   // [16384,512] f32
  const float* S     = (const float*)d_in[1];   // [8192,512]  f32
  const float* coeff = (const float*)d_in[2];   // [1,8192]    f32
  const float* rho   = (const float*)d_in[3];   // [1]         f32
  const float* gamma = (const float*)d_in[4];   // scalar      f32
  float* out = (float*)d_out;

  // ws: Sb 8MB | Xb 16MB | lc2 32KB | ex 64KB | partials 512KB  (~24.6 MB)
  char* ws = (char*)d_ws;
  __bf16* Sb    = (__bf16*)ws;
  __bf16* Xbuf  = (__bf16*)(ws + ((size_t)SROWS * FDIM * 2));
  float*  lc2   = (float*)(ws + ((size_t)SROWS * FDIM * 2) + ((size_t)BROWS * FDIM * 2));
  float*  ex    = lc2 + SROWS;
  float*  parts = ex + BROWS;

  prep_s_kernel<<<SROWS / 4, 256, 0, stream>>>(S, coeff, gamma, Sb, lc2);
  prep_x_kernel<<<BROWS / 4, 256, 0, stream>>>(X, gamma, Xbuf, ex);
  ocsvm_main_kernel<<<NCHUNK * (BROWS / BM), 512, 0, stream>>>(Xbuf, Sb, lc2, ex, gamma, parts);
  reduce_kernel<<<BROWS / 256, 256, 0, stream>>>(parts, rho, out);
}

// Round 13
// 209.186 us; speedup vs baseline: 1.2397x; 1.0367x over previous
//
#include <hip/hip_runtime.h>
#include <stdint.h>
#include <stddef.h>

// Problem geometry
#define BROWS  16384
#define SROWS  8192
#define FDIM   512
#define NCHUNK 8
#define SCHUNK (SROWS / NCHUNK)     // 1024
#define BM     256                  // X rows per block
#define BN     256                  // S cols per S-tile
#define BK     64                   // K per staged chunk
#define NSTILE (SCHUNK / BN)        // 4
#define NKC    (FDIM / BK)          // 8
#define NC     (NSTILE * NKC)       // 32 chunks per block

#define LOG2E 1.44269504088896340736f

typedef __bf16 bf16x8 __attribute__((ext_vector_type(8)));
typedef float  f32x4  __attribute__((ext_vector_type(4)));

__device__ inline void gload16(const void* g, void* l) {
  __builtin_amdgcn_global_load_lds(
      (const __attribute__((address_space(1))) void*)g,
      (__attribute__((address_space(3))) void*)l, 16, 0, 0);
}

// ---------------------------------------------------------------------------
// Prep S: f32 -> bf16, lc2[s] = log2(coeff[s]) - g*log2e*||s||^2  (validated)
// ---------------------------------------------------------------------------
__global__ __launch_bounds__(256) void prep_s_kernel(
    const float* __restrict__ S, const float* __restrict__ coeff,
    const float* __restrict__ gamma, __bf16* __restrict__ Sb,
    float* __restrict__ lc2)
{
  const int lane = threadIdx.x & 63;
  const int wid  = threadIdx.x >> 6;
  const int row  = (blockIdx.x << 2) + wid;
  const float* src = S + ((size_t)row << 9) + (lane << 3);
  float4 a = ((const float4*)src)[0];
  float4 b = ((const float4*)src)[1];
  float sq = a.x*a.x + a.y*a.y + a.z*a.z + a.w*a.w +
             b.x*b.x + b.y*b.y + b.z*b.z + b.w*b.w;
  bf16x8 v;
  v[0]=(__bf16)a.x; v[1]=(__bf16)a.y; v[2]=(__bf16)a.z; v[3]=(__bf16)a.w;
  v[4]=(__bf16)b.x; v[5]=(__bf16)b.y; v[6]=(__bf16)b.z; v[7]=(__bf16)b.w;
  *(bf16x8*)(Sb + ((size_t)row << 9) + (lane << 3)) = v;
  #pragma unroll
  for (int m = 1; m < 64; m <<= 1) sq += __shfl_xor(sq, m, 64);
  if (lane == 0) lc2[row] = log2f(coeff[row]) - gamma[0] * LOG2E * sq;
}

// ---------------------------------------------------------------------------
// Prep X: f32 -> bf16, ex[row] = exp2(-g*log2e*||x||^2)
// ---------------------------------------------------------------------------
__global__ __launch_bounds__(256) void prep_x_kernel(
    const float* __restrict__ X, const float* __restrict__ gamma,
    __bf16* __restrict__ Xb, float* __restrict__ ex)
{
  const int lane = threadIdx.x & 63;
  const int wid  = threadIdx.x >> 6;
  const int row  = (blockIdx.x << 2) + wid;
  const float* src = X + ((size_t)row << 9) + (lane << 3);
  float4 a = ((const float4*)src)[0];
  float4 b = ((const float4*)src)[1];
  float sq = a.x*a.x + a.y*a.y + a.z*a.z + a.w*a.w +
             b.x*b.x + b.y*b.y + b.z*b.z + b.w*b.w;
  bf16x8 v;
  v[0]=(__bf16)a.x; v[1]=(__bf16)a.y; v[2]=(__bf16)a.z; v[3]=(__bf16)a.w;
  v[4]=(__bf16)b.x; v[5]=(__bf16)b.y; v[6]=(__bf16)b.z; v[7]=(__bf16)b.w;
  *(bf16x8*)(Xb + ((size_t)row << 9) + (lane << 3)) = v;
  #pragma unroll
  for (int m = 1; m < 64; m <<= 1) sq += __shfl_xor(sq, m, 64);
  if (lane == 0) ex[row] = exp2f(-gamma[0] * LOG2E * sq);
}

// ---------------------------------------------------------------------------
// Main: 2D register-blocked fused RBF-GEMM — A-affine XCD mapping.
// mtile = bx&63, chunkid = bx>>6  =>  XCD (bx%8) = mtile%8: all 8 chunk-
// passes over an A-tile run on ONE XCD -> A fetched once per XCD (2 MB,
// L2-resident, kept hot by per-chunk restage). B-chunks stream through L2,
// shared by the 8 lockstep co-round blocks. Kills R12's 256 MB of 8x-
// duplicated A-tile L2-miss traffic; vmcnt(0) drain becomes L2-latency.
// Rest identical to R12: 8 waves (2M x 4N), wave = 128x64 (acc 128 AGPR),
// score in LDS (ds_add_f32), A+B dbuf LDS + XOR swizzle, post-barrier STAGE.
// ---------------------------------------------------------------------------
__global__ __launch_bounds__(512, 2) void ocsvm_main_kernel(
    const __bf16* __restrict__ Xb, const __bf16* __restrict__ Sb,
    const float* __restrict__ lc2, const float* __restrict__ ex,
    const float* __restrict__ gamma, float* __restrict__ partials)
{
  __shared__ char lds[131072];        // 2 x (A 32 KB + B 32 KB)
  __shared__ float score_lds[BM];     // per-row score accumulator
  const int tid  = threadIdx.x;
  const int lane = tid & 63;
  const int wid  = tid >> 6;
  const int wm   = wid >> 2;        // 0..1  (M group: 128 rows)
  const int wn   = wid & 3;         // 0..3  (N group: 64 cols)
  const int lr   = lane & 15;
  const int hi   = lane >> 4;

  const int bx      = blockIdx.x;
  const int mtile   = bx & 63;        // XCD = bx%8 = mtile%8 -> A-affine
  const int chunkid = bx >> 6;
  const int m0      = mtile * BM;
  const int chunk0  = chunkid * SCHUNK;

  const float K2 = 2.0f * gamma[0] * LOG2E;

  const char* xb = (const char*)Xb;
  const char* sb = (const char*)Sb;
  const int r0     = tid >> 3;                            // staging row 0..63
  const int srcoff = ((tid & 7) << 4) ^ ((r0 & 7) << 4);  // pre-swizzled src byte

#define STAGE(bufsel, c)                                                      \
  { const int st_ = (c) >> 3, kc_ = (c) & 7;                                  \
    const char* asrc_ = xb + (((size_t)(m0 + r0)) << 10) + (kc_ << 7) + srcoff; \
    const char* bsrc_ = sb + (((size_t)(chunk0 + (st_ << 8) + r0)) << 10)     \
                           + (kc_ << 7) + srcoff;                             \
    char* ad_ = &lds[(bufsel) * 65536 + (tid << 4)];                          \
    _Pragma("unroll")                                                         \
    for (int j = 0; j < 4; ++j) {                                             \
      gload16(asrc_ + j * 65536, ad_ + j * 8192);                             \
      gload16(bsrc_ + j * 65536, ad_ + 32768 + j * 8192);                     \
    } }

  // frag-read swizzled k-offsets (bits 4-6): (ks*64 + hi*16) ^ ((lr&7)<<4)
  const int sw0 = (hi << 4) ^ ((lr & 7) << 4);
  const int sw1 = sw0 ^ 64;

  STAGE(0, 0);   // prologue
  if (tid < BM) score_lds[tid] = 0.0f;   // init before first barrier

  int c = 0;
  for (int st = 0; st < NSTILE; ++st) {
    f32x4 acc[8][4];
    #pragma unroll
    for (int mi = 0; mi < 8; ++mi)
      #pragma unroll
      for (int ni = 0; ni < 4; ++ni) acc[mi][ni] = (f32x4){0.f, 0.f, 0.f, 0.f};

    for (int kc = 0; kc < NKC; ++kc, ++c) {
      // buf-c loads were issued one full chunk of compute ago
      asm volatile("s_waitcnt vmcnt(0)" ::: "memory");
      __builtin_amdgcn_s_barrier();
      asm volatile("" ::: "memory");
      if (c + 1 < NC) STAGE((c + 1) & 1, c + 1);   // post-barrier: dbuf-safe

      const char* bA = &lds[(c & 1) * 65536 + wm * 16384 + lr * 128];
      const char* bB = &lds[(c & 1) * 65536 + 32768 + (wn << 13) + lr * 128];

      __builtin_amdgcn_s_setprio(1);
      #pragma unroll
      for (int ks = 0; ks < 2; ++ks) {
        const int swk = ks ? sw1 : sw0;
        bf16x8 b0 = *(const bf16x8*)(bB + swk);
        bf16x8 b1 = *(const bf16x8*)(bB + swk + 2048);
        bf16x8 b2 = *(const bf16x8*)(bB + swk + 4096);
        bf16x8 b3 = *(const bf16x8*)(bB + swk + 6144);
        #pragma unroll
        for (int mh = 0; mh < 2; ++mh) {
          const char* pa = bA + swk + mh * 8192;
          bf16x8 a0 = *(const bf16x8*)(pa);
          bf16x8 a1 = *(const bf16x8*)(pa + 2048);
          bf16x8 a2 = *(const bf16x8*)(pa + 4096);
          bf16x8 a3 = *(const bf16x8*)(pa + 6144);
          const int mb = mh << 2;
          acc[mb+0][0] = __builtin_amdgcn_mfma_f32_16x16x32_bf16(a0, b0, acc[mb+0][0], 0, 0, 0);
          acc[mb+0][1] = __builtin_amdgcn_mfma_f32_16x16x32_bf16(a0, b1, acc[mb+0][1], 0, 0, 0);
          acc[mb+0][2] = __builtin_amdgcn_mfma_f32_16x16x32_bf16(a0, b2, acc[mb+0][2], 0, 0, 0);
          acc[mb+0][3] = __builtin_amdgcn_mfma_f32_16x16x32_bf16(a0, b3, acc[mb+0][3], 0, 0, 0);
          acc[mb+1][0] = __builtin_amdgcn_mfma_f32_16x16x32_bf16(a1, b0, acc[mb+1][0], 0, 0, 0);
          acc[mb+1][1] = __builtin_amdgcn_mfma_f32_16x16x32_bf16(a1, b1, acc[mb+1][1], 0, 0, 0);
          acc[mb+1][2] = __builtin_amdgcn_mfma_f32_16x16x32_bf16(a1, b2, acc[mb+1][2], 0, 0, 0);
          acc[mb+1][3] = __builtin_amdgcn_mfma_f32_16x16x32_bf16(a1, b3, acc[mb+1][3], 0, 0, 0);
          acc[mb+2][0] = __builtin_amdgcn_mfma_f32_16x16x32_bf16(a2, b0, acc[mb+2][0], 0, 0, 0);
          acc[mb+2][1] = __builtin_amdgcn_mfma_f32_16x16x32_bf16(a2, b1, acc[mb+2][1], 0, 0, 0);
          acc[mb+2][2] = __builtin_amdgcn_mfma_f32_16x16x32_bf16(a2, b2, acc[mb+2][2], 0, 0, 0);
          acc[mb+2][3] = __builtin_amdgcn_mfma_f32_16x16x32_bf16(a2, b3, acc[mb+2][3], 0, 0, 0);
          acc[mb+3][0] = __builtin_amdgcn_mfma_f32_16x16x32_bf16(a3, b0, acc[mb+3][0], 0, 0, 0);
          acc[mb+3][1] = __builtin_amdgcn_mfma_f32_16x16x32_bf16(a3, b1, acc[mb+3][1], 0, 0, 0);
          acc[mb+3][2] = __builtin_amdgcn_mfma_f32_16x16x32_bf16(a3, b2, acc[mb+3][2], 0, 0, 0);
          acc[mb+3][3] = __builtin_amdgcn_mfma_f32_16x16x32_bf16(a3, b3, acc[mb+3][3], 0, 0, 0);
        }
      }
      __builtin_amdgcn_s_setprio(0);
    }

    // epilogue for S-tile st: cols = chunk0 + st*256 + wn*64 + ni*16 + lr.
    // Transient per-lane exp-sum -> 16-lane shfl reduce -> ds_add_f32.
    const float* lc = lc2 + chunk0 + (st << 8) + (wn << 6) + lr;
    const float l0 = lc[0], l1 = lc[16], l2 = lc[32], l3 = lc[48];
    #pragma unroll
    for (int mi = 0; mi < 8; ++mi)
      #pragma unroll
      for (int j = 0; j < 4; ++j) {
        float v = __builtin_amdgcn_exp2f(__builtin_fmaf(K2, acc[mi][0][j], l0))
                + __builtin_amdgcn_exp2f(__builtin_fmaf(K2, acc[mi][1][j], l1))
                + __builtin_amdgcn_exp2f(__builtin_fmaf(K2, acc[mi][2][j], l2))
                + __builtin_amdgcn_exp2f(__builtin_fmaf(K2, acc[mi][3][j], l3));
        v += __shfl_xor(v, 1, 64);
        v += __shfl_xor(v, 2, 64);
        v += __shfl_xor(v, 4, 64);
        v += __shfl_xor(v, 8, 64);
        if (lr == 0)   // C layout (m89): row = (lane>>4)*4 + reg
          atomicAdd(&score_lds[(wm << 7) + (mi << 4) + (hi << 2) + j], v);
      }
  }

  __syncthreads();   // all ds_add_f32 retired
  if (tid < BM) {
    const int row = m0 + tid;
    partials[(size_t)chunkid * BROWS + row] = score_lds[tid] * ex[row];
  }
#undef STAGE
}

// ---------------------------------------------------------------------------
// Final: sum 8 chunk partials, subtract rho.
// ---------------------------------------------------------------------------
__global__ __launch_bounds__(256) void reduce_kernel(
    const float* __restrict__ partials, const float* __restrict__ rho,
    float* __restrict__ out)
{
  const int i = blockIdx.x * 256 + threadIdx.x;
  float s = 0.0f;
  #pragma unroll
  for (int k = 0; k < NCHUNK; ++k) s += partials[(size_t)k * BROWS + i];
  out[i] = s - rho[0];
}

extern "C" void kernel_launch(void* const* d_in, const int* in_sizes, int n_in,
                              void* d_out, int out_size, void* d_ws, size_t ws_size,
                              hipStream_t stream) {
  const float* X     = (const float*)d_in[0];   // [16384,512] f32
  const float* S     = (const float*)d_in[1];   // [8192,512]  f32
  const float* coeff = (const float*)d_in[2];   // [1,8192]    f32
  const float* rho   = (const float*)d_in[3];   // [1]         f32
  const float* gamma = (const float*)d_in[4];   // scalar      f32
  float* out = (float*)d_out;

  // ws: Sb 8MB | Xb 16MB | lc2 32KB | ex 64KB | partials 512KB  (~24.6 MB)
  char* ws = (char*)d_ws;
  __bf16* Sb    = (__bf16*)ws;
  __bf16* Xbuf  = (__bf16*)(ws + ((size_t)SROWS * FDIM * 2));
  float*  lc2   = (float*)(ws + ((size_t)SROWS * FDIM * 2) + ((size_t)BROWS * FDIM * 2));
  float*  ex    = lc2 + SROWS;
  float*  parts = ex + BROWS;

  prep_s_kernel<<<SROWS / 4, 256, 0, stream>>>(S, coeff, gamma, Sb, lc2);
  prep_x_kernel<<<BROWS / 4, 256, 0, stream>>>(X, gamma, Xbuf, ex);
  ocsvm_main_kernel<<<NCHUNK * (BROWS / BM), 512, 0, stream>>>(Xbuf, Sb, lc2, ex, gamma, parts);
  reduce_kernel<<<BROWS / 256, 256, 0, stream>>>(parts, rho, out);
}